// Round 10
// baseline (52.918 us; speedup 1.0000x reference)
//
#include <hip/hip_runtime.h>

// Problem constants (B=8, C=128, H=W=48 -> N=2304)
#define NTOK 2304
#define CC   128

typedef __attribute__((ext_vector_type(8))) short bf16x8;
typedef __attribute__((ext_vector_type(4))) float f32x4;

// round-to-nearest-even fp32 -> bf16
__device__ __forceinline__ unsigned f2bf(float f) {
  unsigned u = __builtin_bit_cast(unsigned, f);
  u += 0x7FFFu + ((u >> 16) & 1u);
  return (u >> 16) & 0xFFFFu;
}
__device__ __forceinline__ unsigned pk2(float a, float b) {
  return f2bf(a) | (f2bf(b) << 16);
}

// async global->LDS, 16B per lane; LDS dest = wave-uniform base + lane*16,
// global src per-lane (guide §5 / m97; size must be literal 16)
__device__ __forceinline__ void g2l16(const void* g, void* l) {
  __builtin_amdgcn_global_load_lds(
      (const __attribute__((address_space(1))) unsigned int*)g,
      (__attribute__((address_space(3))) unsigned int*)l, 16, 0, 0);
}

// Prep (validated R8/R9): ONE pass over x,y. Computes exact fp32 norms
// (sx from x, sy from y; reference quirk: P[i][j] = ||x_i||^2 + ||y_j||^2
// - 2*y_i.x_j) AND writes a bf16 "LDS image": img[b][n] = 256 B row of
// K-contiguous bf16 with slot swizzle slot=(k>>3)^(n&15)^((n>>4)&3)
// pre-applied ((n&15), (n>>4)&3 invariant under 64-aligned tile bases ->
// gemm DMAs rows linearly into LDS).
__global__ __launch_bounds__(256) void pwd_prep(
    const float* __restrict__ x, const float* __restrict__ y,
    char* __restrict__ imgX, char* __restrict__ imgY,
    float* __restrict__ sx, float* __restrict__ sy) {
  __shared__ float part[4][64];
  const int tid = threadIdx.x;
  const int nl  = tid & 63;
  const int cq  = tid >> 6;            // k-quarter: 32 k's = 4 octets
  const int n   = blockIdx.x * 64 + nl;
  const int b   = blockIdx.y;
  const int sel = blockIdx.z;
  const float* src = sel ? y : x;
  char* img = sel ? imgY : imgX;

  const float* p = src + ((size_t)b * CC + cq * 32) * NTOK + n;
  float v[32];
#pragma unroll
  for (int k = 0; k < 32; ++k) v[k] = p[(size_t)k * NTOK];

  float s = 0.f;
#pragma unroll
  for (int k = 0; k < 32; ++k) s = fmaf(v[k], v[k], s);
  part[cq][nl] = s;

  char* row = img + ((size_t)b * NTOK + n) * 256;
  const int swz = (n & 15) ^ ((n >> 4) & 3);
#pragma unroll
  for (int oo = 0; oo < 4; ++oo) {
    const int o = cq * 4 + oo;         // k-octet 0..15
    uint4 wv;
    wv.x = pk2(v[oo * 8 + 0], v[oo * 8 + 1]);
    wv.y = pk2(v[oo * 8 + 2], v[oo * 8 + 3]);
    wv.z = pk2(v[oo * 8 + 4], v[oo * 8 + 5]);
    wv.w = pk2(v[oo * 8 + 6], v[oo * 8 + 7]);
    *(uint4*)(row + ((o ^ swz) * 16)) = wv;
  }
  __syncthreads();
  if (tid < 64) {
    float t = part[0][tid] + part[1][tid] + part[2][tid] + part[3][tid];
    (sel ? sy : sx)[b * NTOK + blockIdx.x * 64 + tid] = t;
  }
}

// Main GEMM, small-tile high-occupancy (R9) with PLAIN stores (A/B vs R9's
// nontemporal: testing the NT-write-amplification theory).
//   D[m=j][n=i] = sum_k x[k][j]*y[k][i]  (= y_i . x_j)
// 64x64 tile, 256 threads (4 waves), wave w owns i-band [16w,16w+16), all 64
// j's. LDS 32KB -> 5 blocks/CU. Staging = 8x global_load_lds dwordx4/thread
// from the pre-swizzled bf16 image.
__global__ __launch_bounds__(256, 5) void pwd_gemm(
    const char* __restrict__ imgX, const char* __restrict__ imgY,
    const float* __restrict__ sx, const float* __restrict__ sy,
    float* __restrict__ out) {
  __shared__ __attribute__((aligned(16))) char smem[32768];
  char* const smX = smem;            // x panel: 64 j-rows * 256 B
  char* const smY = smem + 16384;    // y panel: 64 i-rows * 256 B

  const int tid = threadIdx.x;

  // XCD swizzle: grid 10368 = 8*1296; bid%8 = batch (one batch per XCD L2).
  const int bid = blockIdx.x;
  const int b   = bid & 7;
  const int rem = bid >> 3;            // 0..1295
  const int byy = rem / 36;
  const int bxx = rem - byy * 36;
  const int i0 = byy * 64;             // output rows (i)
  const int j0 = bxx * 64;             // output cols (j)

  const int w  = tid >> 6;             // wave 0..3
  const int l  = tid & 63;
  const int lr = l & 15;
  const int lg = l >> 4;
  const int wi = w * 16;               // wave i band

  // ---------------- stage panels via async DMA ------------------------------
  // wave w copies 4KB chunk w of each 16KB panel (4 x 1KB instructions).
  {
    const char* gx = imgX + ((size_t)b * NTOK + j0) * 256;
    const char* gy = imgY + ((size_t)b * NTOK + i0) * 256;
    const int wb = w * 4096;
    const size_t o0 = (size_t)wb + (size_t)l * 16;
#pragma unroll
    for (int it = 0; it < 4; ++it)
      g2l16(gx + o0 + it * 1024, smX + wb + it * 1024);
#pragma unroll
    for (int it = 0; it < 4; ++it)
      g2l16(gy + o0 + it * 1024, smY + wb + it * 1024);
  }

  // ---------------- hoist norms into registers (in flight over DMA) ---------
  const float sxr = sx[b * NTOK + i0 + wi + lr];        // x norm at row i
  f32x4 syq[4];
#pragma unroll
  for (int mf = 0; mf < 4; ++mf)                         // y norms at j quad
    syq[mf] = *(const f32x4*)(sy + b * NTOK + j0 + mf * 16 + lg * 4);

  __syncthreads();   // drains vmcnt (DMA complete)

  // ---------------- compute: wave tile 64j x 16i ----------------------------
  f32x4 acc[4] = {};
#pragma unroll
  for (int ks = 0; ks < 4; ++ks) {
    const int o = ks * 4 + lg;           // 16B slot (8 k's)
    bf16x8 ax[4], by;
#pragma unroll
    for (int mf = 0; mf < 4; ++mf) {     // A-frag rows = j
      const int n = mf * 16 + lr;
      const int slot = o ^ (n & 15) ^ ((n >> 4) & 3);
      ax[mf] = *(const bf16x8*)(smX + n * 256 + slot * 16);
    }
    {                                    // B-frag rows = i
      const int n = wi + lr;
      const int slot = o ^ (n & 15) ^ ((n >> 4) & 3);
      by = *(const bf16x8*)(smY + n * 256 + slot * 16);
    }
#pragma unroll
    for (int mf = 0; mf < 4; ++mf)
      acc[mf] = __builtin_amdgcn_mfma_f32_16x16x32_bf16(ax[mf], by, acc[mf],
                                                        0, 0, 0);
  }

  // ---------------- epilogue: PLAIN float4 stores along j (L2 merges) -------
  {
    const int i = i0 + wi + lr;
    float* const rowp = out + ((size_t)b * NTOK + i) * NTOK;
#pragma unroll
    for (int mf = 0; mf < 4; ++mf) {
      const int jb = j0 + mf * 16 + lg * 4;
      f32x4 vv;
#pragma unroll
      for (int r = 0; r < 4; ++r)
        vv[r] = sxr + syq[mf][r] - 2.0f * acc[mf][r];
      *(f32x4*)(rowp + jb) = vv;
    }
  }
}

extern "C" void kernel_launch(void* const* d_in, const int* in_sizes, int n_in,
                              void* d_out, int out_size, void* d_ws, size_t ws_size,
                              hipStream_t stream) {
  (void)in_sizes; (void)n_in; (void)out_size; (void)ws_size;
  const float* x = (const float*)d_in[0];
  const float* y = (const float*)d_in[1];
  float* out = (float*)d_out;

  // workspace layout: bf16 images (2 x 4.72 MB) + norms (2 x 73.7 KB)
  char* imgX = (char*)d_ws;
  char* imgY = imgX + (size_t)8 * NTOK * 256;
  float* sx  = (float*)(imgY + (size_t)8 * NTOK * 256);
  float* sy  = sx + 8 * NTOK;

  dim3 gp(NTOK / 64, 8, 2);
  pwd_prep<<<gp, dim3(256), 0, stream>>>(x, y, imgX, imgY, sx, sy);

  dim3 gg(36 * 36 * 8);                  // one 64x64 tile per block
  pwd_gemm<<<gg, dim3(256), 0, stream>>>(imgX, imgY, sx, sy, out);
}

// Round 11
// 43.595 us; speedup vs baseline: 1.2139x; 1.2139x over previous
//
#include <hip/hip_runtime.h>

// Problem constants (B=8, C=128, H=W=48 -> N=2304)
#define NTOK 2304
#define CC   128

typedef __attribute__((ext_vector_type(8))) short bf16x8;
typedef __attribute__((ext_vector_type(4))) float f32x4;

// round-to-nearest-even fp32 -> bf16
__device__ __forceinline__ unsigned f2bf(float f) {
  unsigned u = __builtin_bit_cast(unsigned, f);
  u += 0x7FFFu + ((u >> 16) & 1u);
  return (u >> 16) & 0xFFFFu;
}
__device__ __forceinline__ unsigned pk2(float a, float b) {
  return f2bf(a) | (f2bf(b) << 16);
}

// async global->LDS, 16B per lane; LDS dest = wave-uniform base + lane*16,
// global src per-lane (guide §5 / m97; size must be literal 16)
__device__ __forceinline__ void g2l16(const void* g, void* l) {
  __builtin_amdgcn_global_load_lds(
      (const __attribute__((address_space(1))) unsigned int*)g,
      (__attribute__((address_space(3))) unsigned int*)l, 16, 0, 0);
}

// Prep (validated R8-R10): ONE pass over x,y. Computes exact fp32 norms
// (sx from x, sy from y; reference quirk: P[i][j] = ||x_i||^2 + ||y_j||^2
// - 2*y_i.x_j) AND writes a bf16 "LDS image": img[b][n] = 256 B row of
// K-contiguous bf16 with slot swizzle slot=(k>>3)^(n&15)^((n>>4)&3)
// pre-applied ((n&15), (n>>4)&3 invariant under 64-aligned tile bases ->
// gemm DMAs rows linearly into LDS).
__global__ __launch_bounds__(256) void pwd_prep(
    const float* __restrict__ x, const float* __restrict__ y,
    char* __restrict__ imgX, char* __restrict__ imgY,
    float* __restrict__ sx, float* __restrict__ sy) {
  __shared__ float part[4][64];
  const int tid = threadIdx.x;
  const int nl  = tid & 63;
  const int cq  = tid >> 6;            // k-quarter: 32 k's = 4 octets
  const int n   = blockIdx.x * 64 + nl;
  const int b   = blockIdx.y;
  const int sel = blockIdx.z;
  const float* src = sel ? y : x;
  char* img = sel ? imgY : imgX;

  const float* p = src + ((size_t)b * CC + cq * 32) * NTOK + n;
  float v[32];
#pragma unroll
  for (int k = 0; k < 32; ++k) v[k] = p[(size_t)k * NTOK];

  float s = 0.f;
#pragma unroll
  for (int k = 0; k < 32; ++k) s = fmaf(v[k], v[k], s);
  part[cq][nl] = s;

  char* row = img + ((size_t)b * NTOK + n) * 256;
  const int swz = (n & 15) ^ ((n >> 4) & 3);
#pragma unroll
  for (int oo = 0; oo < 4; ++oo) {
    const int o = cq * 4 + oo;         // k-octet 0..15
    uint4 wv;
    wv.x = pk2(v[oo * 8 + 0], v[oo * 8 + 1]);
    wv.y = pk2(v[oo * 8 + 2], v[oo * 8 + 3]);
    wv.z = pk2(v[oo * 8 + 4], v[oo * 8 + 5]);
    wv.w = pk2(v[oo * 8 + 6], v[oo * 8 + 7]);
    *(uint4*)(row + ((o ^ swz) * 16)) = wv;
  }
  __syncthreads();
  if (tid < 64) {
    float t = part[0][tid] + part[1][tid] + part[2][tid] + part[3][tid];
    (sel ? sy : sx)[b * NTOK + blockIdx.x * 64 + tid] = t;
  }
}

// Main GEMM (R9/R10 base), epilogue routed through LDS so each store
// instruction writes 4 rows x 256 B CONTIGUOUS (vs 16 rows x 64 B) --
// testing the store-granularity theory of the 3.8 vs 7.1 TB/s drain gap.
//   D[m=j][n=i] = sum_k x[k][j]*y[k][i]  (= y_i . x_j)
// 64x64 tile, 256 threads (4 waves), LDS 32KB -> 5 blocks/CU.
// Staging = 8x global_load_lds dwordx4/thread from pre-swizzled bf16 image.
__global__ __launch_bounds__(256, 5) void pwd_gemm(
    const char* __restrict__ imgX, const char* __restrict__ imgY,
    const float* __restrict__ sx, const float* __restrict__ sy,
    float* __restrict__ out) {
  __shared__ __attribute__((aligned(16))) char smem[32768];
  char* const smX = smem;            // x panel: 64 j-rows * 256 B
  char* const smY = smem + 16384;    // y panel: 64 i-rows * 256 B

  const int tid = threadIdx.x;

  // XCD swizzle: grid 10368 = 8*1296; bid%8 = batch (one batch per XCD L2).
  const int bid = blockIdx.x;
  const int b   = bid & 7;
  const int rem = bid >> 3;            // 0..1295
  const int byy = rem / 36;
  const int bxx = rem - byy * 36;
  const int i0 = byy * 64;             // output rows (i)
  const int j0 = bxx * 64;             // output cols (j)

  const int w  = tid >> 6;             // wave 0..3
  const int l  = tid & 63;
  const int lr = l & 15;
  const int lg = l >> 4;
  const int wi = w * 16;               // wave i band

  // ---------------- stage panels via async DMA ------------------------------
  // wave w copies 4KB chunk w of each 16KB panel (4 x 1KB instructions).
  {
    const char* gx = imgX + ((size_t)b * NTOK + j0) * 256;
    const char* gy = imgY + ((size_t)b * NTOK + i0) * 256;
    const int wb = w * 4096;
    const size_t o0 = (size_t)wb + (size_t)l * 16;
#pragma unroll
    for (int it = 0; it < 4; ++it)
      g2l16(gx + o0 + it * 1024, smX + wb + it * 1024);
#pragma unroll
    for (int it = 0; it < 4; ++it)
      g2l16(gy + o0 + it * 1024, smY + wb + it * 1024);
  }

  // ---------------- hoist norms into registers (in flight over DMA) ---------
  const float sxr = sx[b * NTOK + i0 + wi + lr];        // x norm at row i
  f32x4 syq[4];
#pragma unroll
  for (int mf = 0; mf < 4; ++mf)                         // y norms at j quad
    syq[mf] = *(const f32x4*)(sy + b * NTOK + j0 + mf * 16 + lg * 4);

  __syncthreads();   // drains vmcnt (DMA complete)

  // ---------------- compute: wave tile 64j x 16i ----------------------------
  f32x4 acc[4] = {};
#pragma unroll
  for (int ks = 0; ks < 4; ++ks) {
    const int o = ks * 4 + lg;           // 16B slot (8 k's)
    bf16x8 ax[4], by;
#pragma unroll
    for (int mf = 0; mf < 4; ++mf) {     // A-frag rows = j
      const int n = mf * 16 + lr;
      const int slot = o ^ (n & 15) ^ ((n >> 4) & 3);
      ax[mf] = *(const bf16x8*)(smX + n * 256 + slot * 16);
    }
    {                                    // B-frag rows = i
      const int n = wi + lr;
      const int slot = o ^ (n & 15) ^ ((n >> 4) & 3);
      by = *(const bf16x8*)(smY + n * 256 + slot * 16);
    }
#pragma unroll
    for (int mf = 0; mf < 4; ++mf)
      acc[mf] = __builtin_amdgcn_mfma_f32_16x16x32_bf16(ax[mf], by, acc[mf],
                                                        0, 0, 0);
  }

  // ---------------- epilogue: LDS bounce -> contiguous 256B-run stores ------
  // tile[64][64] fp32 (16 KB), 16B chunks XOR-swizzled: chunk addr =
  // row*256 + ((c16 ^ (row&15))*16). Write instr: 16 rows x 4 c16 -> each
  // granule pair hit 2x (free). Read instr: 4 rows x 16 c16 -> 2x (free).
  {
    float* const tile = (float*)smem;    // panels dead after compute
    __syncthreads();
#pragma unroll
    for (int mf = 0; mf < 4; ++mf) {
      f32x4 vv;
#pragma unroll
      for (int r = 0; r < 4; ++r)
        vv[r] = sxr + syq[mf][r] - 2.0f * acc[mf][r];
      const int row = wi + lr;           // local i
      const int c16 = mf * 4 + lg;       // 16B chunk within row (local j/4)
      *(f32x4*)((char*)tile + row * 256 + ((c16 ^ (row & 15)) * 16)) = vv;
    }
    __syncthreads();
    // stream out: instr = 64 consecutive 16B chunks = 4 rows x 256 B contig
#pragma unroll
    for (int it = 0; it < 4; ++it) {
      const int c   = it * 256 + tid;    // chunk id 0..1023
      const int row = c >> 4;
      const int c16 = c & 15;
      f32x4 vv = *(const f32x4*)((char*)tile + row * 256 +
                                 ((c16 ^ (row & 15)) * 16));
      *(f32x4*)(out + ((size_t)b * NTOK + i0 + row) * NTOK + j0 + c16 * 4) = vv;
    }
  }
}

extern "C" void kernel_launch(void* const* d_in, const int* in_sizes, int n_in,
                              void* d_out, int out_size, void* d_ws, size_t ws_size,
                              hipStream_t stream) {
  (void)in_sizes; (void)n_in; (void)out_size; (void)ws_size;
  const float* x = (const float*)d_in[0];
  const float* y = (const float*)d_in[1];
  float* out = (float*)d_out;

  // workspace layout: bf16 images (2 x 4.72 MB) + norms (2 x 73.7 KB)
  char* imgX = (char*)d_ws;
  char* imgY = imgX + (size_t)8 * NTOK * 256;
  float* sx  = (float*)(imgY + (size_t)8 * NTOK * 256);
  float* sy  = sx + 8 * NTOK;

  dim3 gp(NTOK / 64, 8, 2);
  pwd_prep<<<gp, dim3(256), 0, stream>>>(x, y, imgX, imgY, sx, sy);

  dim3 gg(36 * 36 * 8);                  // one 64x64 tile per block
  pwd_gemm<<<gg, dim3(256), 0, stream>>>(imgX, imgY, sx, sy, out);
}